// Round 4
// baseline (308.340 us; speedup 1.0000x reference)
//
#include <hip/hip_runtime.h>
#include <math.h>

typedef short s16x8 __attribute__((ext_vector_type(8)));
typedef float f32x16 __attribute__((ext_vector_type(16)));
typedef unsigned u32x4 __attribute__((ext_vector_type(4)));

#define N_NODES 100000
#define N_EDGESC 1000000
#define NODE_DIM 64
#define NG 31250   // 1e6 / 32 edges per group (exact)

// round-to-nearest-even f32 -> bf16 bits (prep only)
__device__ __forceinline__ unsigned short f2bf(float f){
  unsigned u = __float_as_uint(f);
  u += 0x7fffu + ((u >> 16) & 1u);
  return (unsigned short)(u >> 16);
}

// pack two f32 -> one u32 of 2x bf16 (RNE), single HW op
__device__ __forceinline__ unsigned cvt_pk_bf16(float lo, float hi){
  unsigned r;
  asm("v_cvt_pk_bf16_f32 %0, %1, %2" : "=v"(r) : "v"(lo), "v"(hi));
  return r;
}

// Prep: blocks [0,2048) cast node table f32->bf16; blocks [2048,2176) pack
// W1^T/W2^T into 32x32x16 MFMA A-fragment order:
//   frag f = kf*4 + nt;  elem (lane l, j):  W[k][n],
//   k = kf*16 + (l>>5)*8 + j,  n = nt*32 + (l&31)
__global__ void prep_kernel(const float* __restrict__ node,
                            const float* __restrict__ w1,
                            const float* __restrict__ w2,
                            unsigned short* __restrict__ nodeb,
                            unsigned short* __restrict__ wf){
  const int b = blockIdx.x;
  if (b < 2048){
    int i = b * 256 + threadIdx.x;
    const int n4 = N_NODES * NODE_DIM / 4;
    const int stride = 2048 * 256;
    for (; i < n4; i += stride){
      const float4 v = reinterpret_cast<const float4*>(node)[i];
      ushort4 o;
      o.x = f2bf(v.x); o.y = f2bf(v.y); o.z = f2bf(v.z); o.w = f2bf(v.w);
      reinterpret_cast<ushort4*>(nodeb)[i] = o;
    }
  } else {
    const int i = (b - 2048) * 256 + threadIdx.x;   // 0..32767
    const float* w = (i < 16384) ? w1 : w2;
    const int ii = i & 16383;
    const int f = ii >> 9, rem = ii & 511, l = rem >> 3, j = rem & 7;
    const int kf = f >> 2, nt = f & 3;
    const int k = kf * 16 + (l >> 5) * 8 + j;
    const int n = nt * 32 + (l & 31);
    wf[i] = f2bf(w[k * 128 + n]);
  }
}

// Persistent fused 3-layer edge MLP.  512 blocks x 256 thr (2 blocks/CU,
// 64KB LDS = W1+W2 fragments, staged once, ZERO barriers in main loop).
// Per wave-iteration: one 32-edge group via mfma_f32_32x32x16_bf16.
//   A = W^T frag (n = nt*32 + (lane&31), k = kf*16 + h*8 + j), h = lane>>5
//   B = feat/h1  (edge = lane&31, same k)
//   D: lane holds h[ch = nt*32 + (r&3) + 8*(r>>2) + 4h][edge = lane&31]
// L1->L2 crossover in-register: cvt_pk_bf16 pairs + shfl_xor(.,32) exchange
// (channel bit2 = owner half h -> only lane<->lane+32 movement needed).
__global__ __launch_bounds__(256, 2) void mlp_main(
    const int* __restrict__ eidx,
    const unsigned short* __restrict__ nodeb,
    const unsigned short* __restrict__ wf,     // [2][32][512] bf16 frag-order
    const float* __restrict__ b1, const float* __restrict__ b2,
    const float* __restrict__ w3, const float* __restrict__ b3,
    float* __restrict__ out)
{
  __shared__ unsigned short wlds[32768];   // 64 KB: [layer][frag][lane*8]

  const int tid  = threadIdx.x;
  const int wave = tid >> 6;
  const int lane = tid & 63;
  const int er   = lane & 31;   // edge-in-group / MFMA col
  const int h    = lane >> 5;   // k-half / channel bit2 owner

  // ---- stage BOTH W layers once (lane-linear, conflict-free)
  #pragma unroll
  for (int j = 0; j < 16; ++j){
    const int c = j * 256 + tid;
    reinterpret_cast<int4*>(wlds)[c] = reinterpret_cast<const int4*>(wf)[c];
  }
  __syncthreads();   // the only barrier in the kernel

  const float bias3 = b3[0];

  auto load_idx = [&](long g, int& is, int& id){
    const long e = g * 32 + er;
    is = eidx[e];
    id = eidx[N_EDGESC + e];
  };
  auto gather = [&](int is, int id, s16x8 (&buf)[8]){
    #pragma unroll
    for (int kf = 0; kf < 8; ++kf){
      const int node = (kf < 4) ? is : id;
      const int col = (kf & 3) * 16 + h * 8;
      buf[kf] = *reinterpret_cast<const s16x8*>(nodeb + node * NODE_DIM + col);
    }
  };

  auto compute_store = [&](const s16x8 (&buf)[8], long g){
    f32x16 acc[4];
    #pragma unroll
    for (int nt = 0; nt < 4; ++nt)
      #pragma unroll
      for (int r = 0; r < 16; ++r) acc[nt][r] = 0.f;

    // ---- layer 1
    #pragma unroll
    for (int kf = 0; kf < 8; ++kf)
      #pragma unroll
      for (int nt = 0; nt < 4; ++nt){
        const s16x8 a = *reinterpret_cast<const s16x8*>(
            (const char*)wlds + (kf * 4 + nt) * 1024 + lane * 16);
        acc[nt] = __builtin_amdgcn_mfma_f32_32x32x16_bf16(a, buf[kf], acc[nt], 0, 0, 0);
      }

    // ---- bias + relu in place
    #pragma unroll
    for (int nt = 0; nt < 4; ++nt)
      #pragma unroll
      for (int rq = 0; rq < 4; ++rq){
        const float4 bb = *reinterpret_cast<const float4*>(b1 + nt * 32 + rq * 8 + 4 * h);
        acc[nt][rq*4+0] = fmaxf(acc[nt][rq*4+0] + bb.x, 0.f);
        acc[nt][rq*4+1] = fmaxf(acc[nt][rq*4+1] + bb.y, 0.f);
        acc[nt][rq*4+2] = fmaxf(acc[nt][rq*4+2] + bb.z, 0.f);
        acc[nt][rq*4+3] = fmaxf(acc[nt][rq*4+3] + bb.w, 0.f);
      }

    // ---- in-register crossover: D-layout -> B-frags for layer 2.
    // For frag kf = 2*nt+ks, lane (er,h) needs channels 16kf + 8h + {0..7}:
    //   word0,1 (m 0..3) live in the h=0 lane;  word2,3 (m 4..7) in h=1 lane.
    s16x8 b2f[8];
    #pragma unroll
    for (int nt = 0; nt < 4; ++nt)
      #pragma unroll
      for (int ks = 0; ks < 2; ++ks){
        const unsigned A0 = cvt_pk_bf16(acc[nt][8*ks+0], acc[nt][8*ks+1]); // rq=2ks
        const unsigned A1 = cvt_pk_bf16(acc[nt][8*ks+2], acc[nt][8*ks+3]);
        const unsigned B0 = cvt_pk_bf16(acc[nt][8*ks+4], acc[nt][8*ks+5]); // rq=2ks+1
        const unsigned B1 = cvt_pk_bf16(acc[nt][8*ks+6], acc[nt][8*ks+7]);
        const unsigned x0 = h ? A0 : B0;           // what the partner needs
        const unsigned x1 = h ? A1 : B1;
        const unsigned t0 = (unsigned)__shfl_xor((int)x0, 32);
        const unsigned t1 = (unsigned)__shfl_xor((int)x1, 32);
        u32x4 t;
        t[0] = h ? t0 : A0;
        t[1] = h ? t1 : A1;
        t[2] = h ? B0 : t0;
        t[3] = h ? B1 : t1;
        b2f[2*nt + ks] = __builtin_bit_cast(s16x8, t);
      }

    // ---- layer 2
    #pragma unroll
    for (int nt = 0; nt < 4; ++nt)
      #pragma unroll
      for (int r = 0; r < 16; ++r) acc[nt][r] = 0.f;
    #pragma unroll
    for (int kf = 0; kf < 8; ++kf)
      #pragma unroll
      for (int nt = 0; nt < 4; ++nt){
        const s16x8 a = *reinterpret_cast<const s16x8*>(
            (const char*)wlds + 32768 + (kf * 4 + nt) * 1024 + lane * 16);
        acc[nt] = __builtin_amdgcn_mfma_f32_32x32x16_bf16(a, b2f[kf], acc[nt], 0, 0, 0);
      }

    // ---- layer 3: bias+relu, dot W3, lane<->lane+32 reduce, sigmoid
    float p = 0.f;
    #pragma unroll
    for (int nt = 0; nt < 4; ++nt)
      #pragma unroll
      for (int rq = 0; rq < 4; ++rq){
        const int cb = nt * 32 + rq * 8 + 4 * h;
        const float4 bb = *reinterpret_cast<const float4*>(b2 + cb);
        const float4 ww = *reinterpret_cast<const float4*>(w3 + cb);
        p += fmaxf(acc[nt][rq*4+0] + bb.x, 0.f) * ww.x;
        p += fmaxf(acc[nt][rq*4+1] + bb.y, 0.f) * ww.y;
        p += fmaxf(acc[nt][rq*4+2] + bb.z, 0.f) * ww.z;
        p += fmaxf(acc[nt][rq*4+3] + bb.w, 0.f) * ww.w;
      }
    p += __shfl_xor(p, 32);
    if (h == 0){
      out[g * 32 + er] = 1.f / (1.f + expf(-(p + bias3)));
    }
  };

  // ---- persistent loop, software-pipelined gather (ping-pong buffers)
  const long stride = (long)gridDim.x * 4;
  long g = (long)blockIdx.x * 4 + wave;
  int isA, idA, isB, idB;
  s16x8 bufA[8], bufB[8];

  load_idx(g, isA, idA);
  gather(isA, idA, bufA);
  while (true){
    long gn = g + stride;
    {
      const long gp = (gn < NG) ? gn : g;
      load_idx(gp, isB, idB);
      gather(isB, idB, bufB);
    }
    compute_store(bufA, g);
    g = gn;
    if (g >= NG) break;
    gn = g + stride;
    {
      const long gp = (gn < NG) ? gn : g;
      load_idx(gp, isA, idA);
      gather(isA, idA, bufA);
    }
    compute_store(bufB, g);
    g = gn;
    if (g >= NG) break;
  }
}

extern "C" void kernel_launch(void* const* d_in, const int* in_sizes, int n_in,
                              void* d_out, int out_size, void* d_ws, size_t ws_size,
                              hipStream_t stream){
  const float* node_rep = (const float*)d_in[0];
  const int*   eidx     = (const int*)d_in[1];
  const float* W1 = (const float*)d_in[2];
  const float* b1 = (const float*)d_in[3];
  const float* W2 = (const float*)d_in[4];
  const float* b2 = (const float*)d_in[5];
  const float* W3 = (const float*)d_in[6];
  const float* b3 = (const float*)d_in[7];
  float* out = (float*)d_out;

  unsigned short* nodeb = (unsigned short*)d_ws;
  unsigned short* wf = (unsigned short*)((char*)d_ws + (size_t)N_NODES * NODE_DIM * 2);

  prep_kernel<<<2048 + 128, 256, 0, stream>>>(node_rep, W1, W2, nodeb, wf);

  mlp_main<<<512, 256, 0, stream>>>(eidx, nodeb, wf, b1, b2, W3, b3, out);
}

// Round 5
// 200.772 us; speedup vs baseline: 1.5358x; 1.5358x over previous
//
#include <hip/hip_runtime.h>
#include <math.h>

typedef short s16x8 __attribute__((ext_vector_type(8)));
typedef float f32x16 __attribute__((ext_vector_type(16)));
typedef unsigned u32x4 __attribute__((ext_vector_type(4)));

#define N_NODES 100000
#define N_EDGESC 1000000
#define NODE_DIM 64
#define NG 31250   // 1e6 / 32 edges per group (exact)

// round-to-nearest-even f32 -> bf16 bits (prep only)
__device__ __forceinline__ unsigned short f2bf(float f){
  unsigned u = __float_as_uint(f);
  u += 0x7fffu + ((u >> 16) & 1u);
  return (unsigned short)(u >> 16);
}

// pack two f32 -> one u32 of 2x bf16 (RNE), single HW op
__device__ __forceinline__ unsigned cvt_pk_bf16(float lo, float hi){
  unsigned r;
  asm("v_cvt_pk_bf16_f32 %0, %1, %2" : "=v"(r) : "v"(lo), "v"(hi));
  return r;
}

// Prep: blocks [0,2048) cast node table f32->bf16; blocks [2048,2176) pack
// W1^T/W2^T into 32x32x16 MFMA A-fragment order (R4-verified):
//   frag f = kf*4 + nt;  elem (lane l, j):  W[k][n],
//   k = kf*16 + (l>>5)*8 + j,  n = nt*32 + (l&31)
__global__ void prep_kernel(const float* __restrict__ node,
                            const float* __restrict__ w1,
                            const float* __restrict__ w2,
                            unsigned short* __restrict__ nodeb,
                            unsigned short* __restrict__ wf){
  const int b = blockIdx.x;
  if (b < 2048){
    int i = b * 256 + threadIdx.x;
    const int n4 = N_NODES * NODE_DIM / 4;
    const int stride = 2048 * 256;
    for (; i < n4; i += stride){
      const float4 v = reinterpret_cast<const float4*>(node)[i];
      ushort4 o;
      o.x = f2bf(v.x); o.y = f2bf(v.y); o.z = f2bf(v.z); o.w = f2bf(v.w);
      reinterpret_cast<ushort4*>(nodeb)[i] = o;
    }
  } else {
    const int i = (b - 2048) * 256 + threadIdx.x;   // 0..32767
    const float* w = (i < 16384) ? w1 : w2;
    const int ii = i & 16383;
    const int f = ii >> 9, rem = ii & 511, l = rem >> 3, j = rem & 7;
    const int kf = f >> 2, nt = f & 3;
    const int k = kf * 16 + (l >> 5) * 8 + j;
    const int n = nt * 32 + (l & 31);
    wf[i] = f2bf(w[k * 128 + n]);
  }
}

// Fused 3-layer edge MLP, non-persistent.  Block = 4 waves; each wave owns
// TWO 32-edge groups (64 edges) per pass, sharing every A-fragment LDS read
// across both groups (halves LDS-A traffic per edge vs one-group-per-wave).
// W1+W2 staged once per block into 64KB LDS; zero barriers after staging.
// Contiguous edge->block map (gather L2 locality as in R1/R2).
//   A = W^T frag (n = nt*32 + (lane&31), k = kf*16 + h*8 + j), h = lane>>5
//   B = feat/h1  (edge = lane&31, same k)
//   D: lane holds h[ch = nt*32 + (r&3) + 8*(r>>2) + 4h][edge = lane&31]
// L1->L2 crossover fully in-register: cvt_pk_bf16 + shfl_xor(.,32) (verified R4).
__global__ __launch_bounds__(256, 2) void mlp_main(
    const int* __restrict__ eidx,
    const unsigned short* __restrict__ nodeb,
    const unsigned short* __restrict__ wf,     // [2][32][512] bf16 frag-order
    const float* __restrict__ b1, const float* __restrict__ b2,
    const float* __restrict__ w3, const float* __restrict__ b3,
    float* __restrict__ out)
{
  __shared__ unsigned short wlds[32768];   // 64 KB: [layer][frag][lane*16B]

  const int tid  = threadIdx.x;
  const int wave = tid >> 6;
  const int lane = tid & 63;
  const int er   = lane & 31;   // edge-in-group / MFMA col
  const int h    = lane >> 5;   // k-half / channel bit2 owner

  // ---- stage BOTH W layers once (lane-linear, conflict-free)
  #pragma unroll
  for (int j = 0; j < 16; ++j){
    const int c = j * 256 + tid;
    reinterpret_cast<int4*>(wlds)[c] = reinterpret_cast<const int4*>(wf)[c];
  }
  __syncthreads();   // the only barrier

  const long g0 = (long)blockIdx.x * 8 + wave * 2;
  const long g1 = g0 + 1;
  const bool v0 = (g0 < NG), v1 = (g1 < NG);
  const long ga = v0 ? g0 : 0;
  const long gb = v1 ? g1 : ga;

  // ---- edge indices (coalesced) then 16 independent gather loads
  const int isA = eidx[ga * 32 + er];
  const int idA = eidx[N_EDGESC + ga * 32 + er];
  const int isB = eidx[gb * 32 + er];
  const int idB = eidx[N_EDGESC + gb * 32 + er];

  s16x8 bufA[8], bufB[8];
  #pragma unroll
  for (int kf = 0; kf < 8; ++kf){
    const int col = (kf & 3) * 16 + h * 8;
    const int na = ((kf < 4) ? isA : idA);
    const int nb = ((kf < 4) ? isB : idB);
    bufA[kf] = *reinterpret_cast<const s16x8*>(nodeb + na * NODE_DIM + col);
    bufB[kf] = *reinterpret_cast<const s16x8*>(nodeb + nb * NODE_DIM + col);
  }

  f32x16 acc[2][4];
  #pragma unroll
  for (int gi = 0; gi < 2; ++gi)
    #pragma unroll
    for (int nt = 0; nt < 4; ++nt)
      #pragma unroll
      for (int r = 0; r < 16; ++r) acc[gi][nt][r] = 0.f;

  // ---- layer 1: one A-read feeds both groups' MFMAs
  #pragma unroll
  for (int kf = 0; kf < 8; ++kf)
    #pragma unroll
    for (int nt = 0; nt < 4; ++nt){
      const s16x8 a = *reinterpret_cast<const s16x8*>(
          (const char*)wlds + (kf * 4 + nt) * 1024 + lane * 16);
      acc[0][nt] = __builtin_amdgcn_mfma_f32_32x32x16_bf16(a, bufA[kf], acc[0][nt], 0, 0, 0);
      acc[1][nt] = __builtin_amdgcn_mfma_f32_32x32x16_bf16(a, bufB[kf], acc[1][nt], 0, 0, 0);
    }

  // ---- bias + relu in place (both groups)
  #pragma unroll
  for (int gi = 0; gi < 2; ++gi)
    #pragma unroll
    for (int nt = 0; nt < 4; ++nt)
      #pragma unroll
      for (int rq = 0; rq < 4; ++rq){
        const float4 bb = *reinterpret_cast<const float4*>(b1 + nt * 32 + rq * 8 + 4 * h);
        acc[gi][nt][rq*4+0] = fmaxf(acc[gi][nt][rq*4+0] + bb.x, 0.f);
        acc[gi][nt][rq*4+1] = fmaxf(acc[gi][nt][rq*4+1] + bb.y, 0.f);
        acc[gi][nt][rq*4+2] = fmaxf(acc[gi][nt][rq*4+2] + bb.z, 0.f);
        acc[gi][nt][rq*4+3] = fmaxf(acc[gi][nt][rq*4+3] + bb.w, 0.f);
      }

  // ---- in-register crossover (R4-verified): D-layout -> B-frags for layer 2
  s16x8 b2fA[8], b2fB[8];
  #pragma unroll
  for (int gi = 0; gi < 2; ++gi){
    s16x8* b2f = gi ? b2fB : b2fA;
    #pragma unroll
    for (int nt = 0; nt < 4; ++nt)
      #pragma unroll
      for (int ks = 0; ks < 2; ++ks){
        const unsigned A0 = cvt_pk_bf16(acc[gi][nt][8*ks+0], acc[gi][nt][8*ks+1]);
        const unsigned A1 = cvt_pk_bf16(acc[gi][nt][8*ks+2], acc[gi][nt][8*ks+3]);
        const unsigned B0 = cvt_pk_bf16(acc[gi][nt][8*ks+4], acc[gi][nt][8*ks+5]);
        const unsigned B1 = cvt_pk_bf16(acc[gi][nt][8*ks+6], acc[gi][nt][8*ks+7]);
        const unsigned x0 = h ? A0 : B0;           // what the partner needs
        const unsigned x1 = h ? A1 : B1;
        const unsigned t0 = (unsigned)__shfl_xor((int)x0, 32);
        const unsigned t1 = (unsigned)__shfl_xor((int)x1, 32);
        u32x4 t;
        t[0] = h ? t0 : A0;
        t[1] = h ? t1 : A1;
        t[2] = h ? B0 : t0;
        t[3] = h ? B1 : t1;
        b2f[2*nt + ks] = __builtin_bit_cast(s16x8, t);
      }
  }

  // ---- layer 2: shared A-reads again
  #pragma unroll
  for (int gi = 0; gi < 2; ++gi)
    #pragma unroll
    for (int nt = 0; nt < 4; ++nt)
      #pragma unroll
      for (int r = 0; r < 16; ++r) acc[gi][nt][r] = 0.f;
  #pragma unroll
  for (int kf = 0; kf < 8; ++kf)
    #pragma unroll
    for (int nt = 0; nt < 4; ++nt){
      const s16x8 a = *reinterpret_cast<const s16x8*>(
          (const char*)wlds + 32768 + (kf * 4 + nt) * 1024 + lane * 16);
      acc[0][nt] = __builtin_amdgcn_mfma_f32_32x32x16_bf16(a, b2fA[kf], acc[0][nt], 0, 0, 0);
      acc[1][nt] = __builtin_amdgcn_mfma_f32_32x32x16_bf16(a, b2fB[kf], acc[1][nt], 0, 0, 0);
    }

  // ---- layer 3: bias+relu, dot W3, lane<->lane+32 reduce, sigmoid
  const float bias3 = b3[0];
  #pragma unroll
  for (int gi = 0; gi < 2; ++gi){
    float p = 0.f;
    #pragma unroll
    for (int nt = 0; nt < 4; ++nt)
      #pragma unroll
      for (int rq = 0; rq < 4; ++rq){
        const int cb = nt * 32 + rq * 8 + 4 * h;
        const float4 bb = *reinterpret_cast<const float4*>(b2 + cb);
        const float4 ww = *reinterpret_cast<const float4*>(w3 + cb);
        p += fmaxf(acc[gi][nt][rq*4+0] + bb.x, 0.f) * ww.x;
        p += fmaxf(acc[gi][nt][rq*4+1] + bb.y, 0.f) * ww.y;
        p += fmaxf(acc[gi][nt][rq*4+2] + bb.z, 0.f) * ww.z;
        p += fmaxf(acc[gi][nt][rq*4+3] + bb.w, 0.f) * ww.w;
      }
    p += __shfl_xor(p, 32);
    const long g = gi ? g1 : g0;
    const bool v = gi ? v1 : v0;
    if (h == 0 && v){
      out[g * 32 + er] = 1.f / (1.f + expf(-(p + bias3)));
    }
  }
}

extern "C" void kernel_launch(void* const* d_in, const int* in_sizes, int n_in,
                              void* d_out, int out_size, void* d_ws, size_t ws_size,
                              hipStream_t stream){
  const float* node_rep = (const float*)d_in[0];
  const int*   eidx     = (const int*)d_in[1];
  const float* W1 = (const float*)d_in[2];
  const float* b1 = (const float*)d_in[3];
  const float* W2 = (const float*)d_in[4];
  const float* b2 = (const float*)d_in[5];
  const float* W3 = (const float*)d_in[6];
  const float* b3 = (const float*)d_in[7];
  float* out = (float*)d_out;

  unsigned short* nodeb = (unsigned short*)d_ws;
  unsigned short* wf = (unsigned short*)((char*)d_ws + (size_t)N_NODES * NODE_DIM * 2);

  prep_kernel<<<2048 + 128, 256, 0, stream>>>(node_rep, W1, W2, nodeb, wf);

  const int nblocks = (NG + 7) / 8;   // 8 groups (256 edges) per block
  mlp_main<<<nblocks, 256, 0, stream>>>(eidx, nodeb, wf, b1, b2, W3, b3, out);
}

// Round 6
// 179.236 us; speedup vs baseline: 1.7203x; 1.1202x over previous
//
#include <hip/hip_runtime.h>
#include <math.h>

typedef short s16x8 __attribute__((ext_vector_type(8)));
typedef float f32x16 __attribute__((ext_vector_type(16)));
typedef float f32x2 __attribute__((ext_vector_type(2)));
typedef unsigned u32x4 __attribute__((ext_vector_type(4)));

#define N_NODES 100000
#define N_EDGESC 1000000
#define NODE_DIM 64
#define NG 31250        // 1e6 / 32 edges per group (exact)
#define GPB 32          // groups per block (4 waves x 2 groups x 4 passes)
#define NPASS 4

// round-to-nearest-even f32 -> bf16 bits (prep only)
__device__ __forceinline__ unsigned short f2bf(float f){
  unsigned u = __float_as_uint(f);
  u += 0x7fffu + ((u >> 16) & 1u);
  return (unsigned short)(u >> 16);
}

// pack two f32 -> one u32 of 2x bf16 (RNE), single HW op
__device__ __forceinline__ unsigned cvt_pk_bf16(float lo, float hi){
  unsigned r;
  asm("v_cvt_pk_bf16_f32 %0, %1, %2" : "=v"(r) : "v"(lo), "v"(hi));
  return r;
}

// 2x fp8(e4m3, low 16 bits of src) -> 2x f32 (HW)
__device__ __forceinline__ f32x2 cvt_pk_f32_fp8(unsigned w){
  f32x2 r;
  asm("v_cvt_pk_f32_fp8 %0, %1" : "=v"(r) : "v"(w));
  return r;
}

// dequant one 8-byte fp8 pair (dlo,dhi) -> bf16 MFMA fragment
__device__ __forceinline__ s16x8 deq_frag(unsigned dlo, unsigned dhi){
  const f32x2 f01 = cvt_pk_f32_fp8(dlo);
  const f32x2 f23 = cvt_pk_f32_fp8(dlo >> 16);
  const f32x2 f45 = cvt_pk_f32_fp8(dhi);
  const f32x2 f67 = cvt_pk_f32_fp8(dhi >> 16);
  u32x4 r;
  r[0] = cvt_pk_bf16(f01[0], f01[1]);
  r[1] = cvt_pk_bf16(f23[0], f23[1]);
  r[2] = cvt_pk_bf16(f45[0], f45[1]);
  r[3] = cvt_pk_bf16(f67[0], f67[1]);
  return __builtin_bit_cast(s16x8, r);
}

// Prep: blocks [0,2048) cast node table f32 -> fp8 e4m3 (6.4 MB, 64B rows =
// exactly one cache line).  Blocks [2048,2176) pack W1^T/W2^T into 32x32x16
// A-fragment order.  W1's k-rows are PERMUTED so that a lane's gathered
// 32B half-row is contiguous:  frag kf, lane l, elem j  <->  feature
// half*64 + (l>>5)*32 + (kf&3)*8 + j   (half = kf>>2: 0=src, 1=dst).
// W2 keeps the plain k = kf*16 + (l>>5)*8 + j order (matches crossover).
__global__ void prep_kernel(const float* __restrict__ node,
                            const float* __restrict__ w1,
                            const float* __restrict__ w2,
                            unsigned* __restrict__ nodef,   // fp8, 4 per u32
                            unsigned short* __restrict__ wf){
  const int b = blockIdx.x;
  if (b < 2048){
    int i = b * 256 + threadIdx.x;
    const int n4 = N_NODES * NODE_DIM / 4;
    const int stride = 2048 * 256;
    for (; i < n4; i += stride){
      const float4 v = reinterpret_cast<const float4*>(node)[i];
      unsigned lo = 0, hi = 0;
      asm("v_cvt_pk_fp8_f32 %0, %1, %2" : "+v"(lo) : "v"(v.x), "v"(v.y));
      asm("v_cvt_pk_fp8_f32 %0, %1, %2" : "+v"(hi) : "v"(v.z), "v"(v.w));
      nodef[i] = (lo & 0xffffu) | (hi << 16);
    }
  } else {
    const int i = (b - 2048) * 256 + threadIdx.x;   // 0..32767
    const int ii = i & 16383;
    const int f = ii >> 9, rem = ii & 511, l = rem >> 3, j = rem & 7;
    const int kf = f >> 2, nt = f & 3;
    const int h = l >> 5, n = nt * 32 + (l & 31);
    if (i < 16384){
      const int feat = (kf >> 2) * 64 + h * 32 + (kf & 3) * 8 + j;  // permuted
      wf[i] = f2bf(w1[feat * 128 + n]);
    } else {
      const int k = kf * 16 + h * 8 + j;                            // plain
      wf[i] = f2bf(w2[k * 128 + n]);
    }
  }
}

// Fused 3-layer edge MLP.  Block = 4 waves x NPASS passes x 2 groups
// (32 contiguous groups = 1024 edges per block).  W1+W2 staged once into
// 64KB LDS (zero barriers after staging).  Node features gathered as fp8
// (one 64B line per node), dequantized in-register to bf16.
//   A = W^T frag (n = nt*32 + (lane&31), k-frag kf, h = lane>>5)
//   B = feat/h1  (edge = lane&31)
//   D: lane holds h[ch = nt*32 + (r&3) + 8*(r>>2) + 4h][edge = lane&31]
// L1->L2 crossover fully in-register: cvt_pk_bf16 + shfl_xor(.,32) (verified R4/R5).
__global__ __launch_bounds__(256, 2) void mlp_main(
    const int* __restrict__ eidx,
    const unsigned char* __restrict__ nodef,   // [N][64] fp8 e4m3
    const unsigned short* __restrict__ wf,     // [2][32][512] bf16 frag-order
    const float* __restrict__ b1, const float* __restrict__ b2,
    const float* __restrict__ w3, const float* __restrict__ b3,
    float* __restrict__ out)
{
  __shared__ unsigned short wlds[32768];   // 64 KB: [layer][frag][lane*16B]

  const int tid  = threadIdx.x;
  const int wave = tid >> 6;
  const int lane = tid & 63;
  const int er   = lane & 31;   // edge-in-group / MFMA col
  const int h    = lane >> 5;   // k-half owner / feature half

  // ---- stage BOTH W layers once (lane-linear, conflict-free)
  #pragma unroll
  for (int j = 0; j < 16; ++j){
    const int c = j * 256 + tid;
    reinterpret_cast<int4*>(wlds)[c] = reinterpret_cast<const int4*>(wf)[c];
  }
  __syncthreads();   // the only barrier

  const float bias3 = b3[0];

  for (int p = 0; p < NPASS; ++p){
    const long g0 = (long)blockIdx.x * GPB + p * 8 + wave * 2;
    const long g1 = g0 + 1;
    const bool v0 = (g0 < NG), v1 = (g1 < NG);
    const long ga = v0 ? g0 : 0;
    const long gb = v1 ? g1 : ga;

    // ---- edge indices (coalesced)
    const int isA = eidx[ga * 32 + er];
    const int idA = eidx[N_EDGESC + ga * 32 + er];
    const int isB = eidx[gb * 32 + er];
    const int idB = eidx[N_EDGESC + gb * 32 + er];

    // ---- fp8 gather: per lane one contiguous 32B half-row per node
    // (lanes (er,0)+(er,1) together cover the full 64B line)
    u32x4 rA[4], rB[4];
    {
      const unsigned char* sA = nodef + (size_t)isA * 64 + h * 32;
      const unsigned char* dA = nodef + (size_t)idA * 64 + h * 32;
      const unsigned char* sB = nodef + (size_t)isB * 64 + h * 32;
      const unsigned char* dB = nodef + (size_t)idB * 64 + h * 32;
      rA[0] = *reinterpret_cast<const u32x4*>(sA);
      rA[1] = *reinterpret_cast<const u32x4*>(sA + 16);
      rA[2] = *reinterpret_cast<const u32x4*>(dA);
      rA[3] = *reinterpret_cast<const u32x4*>(dA + 16);
      rB[0] = *reinterpret_cast<const u32x4*>(sB);
      rB[1] = *reinterpret_cast<const u32x4*>(sB + 16);
      rB[2] = *reinterpret_cast<const u32x4*>(dB);
      rB[3] = *reinterpret_cast<const u32x4*>(dB + 16);
    }

    f32x16 acc[2][4];
    #pragma unroll
    for (int gi = 0; gi < 2; ++gi)
      #pragma unroll
      for (int nt = 0; nt < 4; ++nt)
        #pragma unroll
        for (int r = 0; r < 16; ++r) acc[gi][nt][r] = 0.f;

    // ---- layer 1: dequant frag kf once per group, share A-read across groups
    // frag kf <-> dwords (kf*2, kf*2+1) of the 8-dword (src0,src1,dst0,dst1) quad
    #pragma unroll
    for (int kf = 0; kf < 8; ++kf){
      const s16x8 fA = deq_frag(rA[kf >> 1][(kf & 1) * 2], rA[kf >> 1][(kf & 1) * 2 + 1]);
      const s16x8 fB = deq_frag(rB[kf >> 1][(kf & 1) * 2], rB[kf >> 1][(kf & 1) * 2 + 1]);
      #pragma unroll
      for (int nt = 0; nt < 4; ++nt){
        const s16x8 a = *reinterpret_cast<const s16x8*>(
            (const char*)wlds + (kf * 4 + nt) * 1024 + lane * 16);
        acc[0][nt] = __builtin_amdgcn_mfma_f32_32x32x16_bf16(a, fA, acc[0][nt], 0, 0, 0);
        acc[1][nt] = __builtin_amdgcn_mfma_f32_32x32x16_bf16(a, fB, acc[1][nt], 0, 0, 0);
      }
    }

    // ---- bias + relu in place (both groups)
    #pragma unroll
    for (int gi = 0; gi < 2; ++gi)
      #pragma unroll
      for (int nt = 0; nt < 4; ++nt)
        #pragma unroll
        for (int rq = 0; rq < 4; ++rq){
          const float4 bb = *reinterpret_cast<const float4*>(b1 + nt * 32 + rq * 8 + 4 * h);
          acc[gi][nt][rq*4+0] = fmaxf(acc[gi][nt][rq*4+0] + bb.x, 0.f);
          acc[gi][nt][rq*4+1] = fmaxf(acc[gi][nt][rq*4+1] + bb.y, 0.f);
          acc[gi][nt][rq*4+2] = fmaxf(acc[gi][nt][rq*4+2] + bb.z, 0.f);
          acc[gi][nt][rq*4+3] = fmaxf(acc[gi][nt][rq*4+3] + bb.w, 0.f);
        }

    // ---- in-register crossover (verified): D-layout -> B-frags for layer 2
    s16x8 b2fA[8], b2fB[8];
    #pragma unroll
    for (int gi = 0; gi < 2; ++gi){
      s16x8* b2f = gi ? b2fB : b2fA;
      #pragma unroll
      for (int nt = 0; nt < 4; ++nt)
        #pragma unroll
        for (int ks = 0; ks < 2; ++ks){
          const unsigned A0 = cvt_pk_bf16(acc[gi][nt][8*ks+0], acc[gi][nt][8*ks+1]);
          const unsigned A1 = cvt_pk_bf16(acc[gi][nt][8*ks+2], acc[gi][nt][8*ks+3]);
          const unsigned B0 = cvt_pk_bf16(acc[gi][nt][8*ks+4], acc[gi][nt][8*ks+5]);
          const unsigned B1 = cvt_pk_bf16(acc[gi][nt][8*ks+6], acc[gi][nt][8*ks+7]);
          const unsigned x0 = h ? A0 : B0;           // what the partner needs
          const unsigned x1 = h ? A1 : B1;
          const unsigned t0 = (unsigned)__shfl_xor((int)x0, 32);
          const unsigned t1 = (unsigned)__shfl_xor((int)x1, 32);
          u32x4 t;
          t[0] = h ? t0 : A0;
          t[1] = h ? t1 : A1;
          t[2] = h ? B0 : t0;
          t[3] = h ? B1 : t1;
          b2f[2*nt + ks] = __builtin_bit_cast(s16x8, t);
        }
    }

    // ---- layer 2: shared A-reads again
    #pragma unroll
    for (int gi = 0; gi < 2; ++gi)
      #pragma unroll
      for (int nt = 0; nt < 4; ++nt)
        #pragma unroll
        for (int r = 0; r < 16; ++r) acc[gi][nt][r] = 0.f;
    #pragma unroll
    for (int kf = 0; kf < 8; ++kf)
      #pragma unroll
      for (int nt = 0; nt < 4; ++nt){
        const s16x8 a = *reinterpret_cast<const s16x8*>(
            (const char*)wlds + 32768 + (kf * 4 + nt) * 1024 + lane * 16);
        acc[0][nt] = __builtin_amdgcn_mfma_f32_32x32x16_bf16(a, b2fA[kf], acc[0][nt], 0, 0, 0);
        acc[1][nt] = __builtin_amdgcn_mfma_f32_32x32x16_bf16(a, b2fB[kf], acc[1][nt], 0, 0, 0);
      }

    // ---- layer 3: bias+relu, dot W3, lane<->lane+32 reduce, sigmoid
    #pragma unroll
    for (int gi = 0; gi < 2; ++gi){
      float pv = 0.f;
      #pragma unroll
      for (int nt = 0; nt < 4; ++nt)
        #pragma unroll
        for (int rq = 0; rq < 4; ++rq){
          const int cb = nt * 32 + rq * 8 + 4 * h;
          const float4 bb = *reinterpret_cast<const float4*>(b2 + cb);
          const float4 ww = *reinterpret_cast<const float4*>(w3 + cb);
          pv += fmaxf(acc[gi][nt][rq*4+0] + bb.x, 0.f) * ww.x;
          pv += fmaxf(acc[gi][nt][rq*4+1] + bb.y, 0.f) * ww.y;
          pv += fmaxf(acc[gi][nt][rq*4+2] + bb.z, 0.f) * ww.z;
          pv += fmaxf(acc[gi][nt][rq*4+3] + bb.w, 0.f) * ww.w;
        }
      pv += __shfl_xor(pv, 32);
      const long g = gi ? g1 : g0;
      const bool v = gi ? v1 : v0;
      if (h == 0 && v){
        out[g * 32 + er] = 1.f / (1.f + expf(-(pv + bias3)));
      }
    }
  }
}

extern "C" void kernel_launch(void* const* d_in, const int* in_sizes, int n_in,
                              void* d_out, int out_size, void* d_ws, size_t ws_size,
                              hipStream_t stream){
  const float* node_rep = (const float*)d_in[0];
  const int*   eidx     = (const int*)d_in[1];
  const float* W1 = (const float*)d_in[2];
  const float* b1 = (const float*)d_in[3];
  const float* W2 = (const float*)d_in[4];
  const float* b2 = (const float*)d_in[5];
  const float* W3 = (const float*)d_in[6];
  const float* b3 = (const float*)d_in[7];
  float* out = (float*)d_out;

  unsigned* nodef = (unsigned*)d_ws;                                   // 6.4 MB fp8
  unsigned short* wf = (unsigned short*)((char*)d_ws + (size_t)N_NODES * NODE_DIM);

  prep_kernel<<<2048 + 128, 256, 0, stream>>>(node_rep, W1, W2, nodef, wf);

  const int nblocks = (NG + GPB - 1) / GPB;   // 977
  mlp_main<<<nblocks, 256, 0, stream>>>(eidx, (const unsigned char*)nodef, wf,
                                        b1, b2, W3, b3, out);
}